// Round 2
// baseline (439.568 us; speedup 1.0000x reference)
//
#include <hip/hip_runtime.h>
#include <hip/hip_bf16.h>

// KANLinear fused: LayerNorm -> {relu, cubic B-spline basis} -> single bf16 MFMA GEMM.
// N=32768 rows, F=512, U=512. K = F*8 = 4096 ([relu, b0..b5, 0] per feature).
// R4: fix LDS duplication (shared arrays declared ONCE in the __global__ wrapper,
// passed into both template bodies). 64x512 tile (full U), 4 waves, grid=512 ->
// 72 KB LDS/block -> 2 independent blocks/CU (cross-block MFMA/VALU overlap).
// Double-buffered LDS, one __syncthreads per K-step.

#define N_ROWS 32768
#define F_DIM  512
#define U_DIM  512
#define K_DIM  4096

typedef short short8 __attribute__((ext_vector_type(8)));
typedef float floatx4 __attribute__((ext_vector_type(4)));

__device__ __forceinline__ float bf2f(unsigned short h) {
    return __uint_as_float(((unsigned int)h) << 16);
}
__device__ __forceinline__ bool probe_bf16(const void* grid) {
    // fp32: grid[0] == -3.0f exactly (0xC0400000). bf16-packed: 0xC015C040.
    return ((const unsigned int*)grid)[0] != 0xC0400000u;
}
template <bool B16>
__device__ __forceinline__ float ldf(const void* p, int i) {
    return B16 ? bf2f(((const unsigned short*)p)[i]) : ((const float*)p)[i];
}
template <bool B16>
__device__ __forceinline__ void ld4(const void* p, int i, float* o) {
    if (B16) {
        ushort4 v = *(const ushort4*)((const unsigned short*)p + i);
        o[0] = bf2f(v.x); o[1] = bf2f(v.y); o[2] = bf2f(v.z); o[3] = bf2f(v.w);
    } else {
        float4 v = *(const float4*)((const float*)p + i);
        o[0] = v.x; o[1] = v.y; o[2] = v.z; o[3] = v.w;
    }
}
__device__ __forceinline__ unsigned int pk2(float lo, float hi) {
    __hip_bfloat162 h = __float22bfloat162_rn(make_float2(lo, hi));
    return *reinterpret_cast<unsigned int*>(&h);
}

// ---------------- prep: per-row LayerNorm stats + Wt[u][k] build ----------------
template <bool B16>
__device__ __forceinline__ void ln_stats_body(const void* __restrict__ x,
                                              float2* __restrict__ stats, int bid) {
    int wave = threadIdx.x >> 6, lane = threadIdx.x & 63;
    int row = bid * 4 + wave;
    float v[8];
    ld4<B16>(x, row * F_DIM + lane * 8, v);
    ld4<B16>(x, row * F_DIM + lane * 8 + 4, v + 4);
    float s = 0.f, s2 = 0.f;
#pragma unroll
    for (int k = 0; k < 8; ++k) { s += v[k]; s2 += v[k] * v[k]; }
#pragma unroll
    for (int off = 32; off > 0; off >>= 1) {
        s  += __shfl_xor(s, off);
        s2 += __shfl_xor(s2, off);
    }
    if (lane == 0) {
        float mean = s * (1.0f / F_DIM);
        float var  = s2 * (1.0f / F_DIM) - mean * mean;
        stats[row] = make_float2(mean, rsqrtf(var + 1e-3f));
    }
}
template <bool B16>
__device__ __forceinline__ void build_wt_body(const void* __restrict__ bw,
                                              const void* __restrict__ sw,
                                              unsigned short* __restrict__ wt, int bid) {
    int idx = bid * 256 + threadIdx.x;  // 0 .. 512*128
    int u = idx & 511;
    int fq = idx >> 9;  // 0..127 -> features fq*4 .. fq*4+3
#pragma unroll
    for (int i = 0; i < 4; ++i) {
        int f = fq * 4 + i;
        uint4 w;
        w.x = pk2(ldf<B16>(bw, f * U_DIM + u),            ldf<B16>(sw, (f * 6 + 0) * U_DIM + u));
        w.y = pk2(ldf<B16>(sw, (f * 6 + 1) * U_DIM + u),  ldf<B16>(sw, (f * 6 + 2) * U_DIM + u));
        w.z = pk2(ldf<B16>(sw, (f * 6 + 3) * U_DIM + u),  ldf<B16>(sw, (f * 6 + 4) * U_DIM + u));
        w.w = pk2(ldf<B16>(sw, (f * 6 + 5) * U_DIM + u),  0.f);
        *(uint4*)(wt + (size_t)u * K_DIM + f * 8) = w;
    }
}
__global__ __launch_bounds__(256) void prep_k(const void* __restrict__ x,
                                              const void* __restrict__ bw,
                                              const void* __restrict__ sw,
                                              const void* __restrict__ grid,
                                              float2* __restrict__ stats,
                                              unsigned short* __restrict__ wt) {
    int bid = blockIdx.x;
    if (probe_bf16(grid)) {
        if (bid < N_ROWS / 4) ln_stats_body<true>(x, stats, bid);
        else                  build_wt_body<true>(bw, sw, wt, bid - N_ROWS / 4);
    } else {
        if (bid < N_ROWS / 4) ln_stats_body<false>(x, stats, bid);
        else                  build_wt_body<false>(bw, sw, wt, bid - N_ROWS / 4);
    }
}

// ---------------- A-element generator: [relu, b0..b5, 0] packed to 4x bf16x2 ----
template <bool B16>
__device__ __forceinline__ uint4 gen_a_pack(const void* __restrict__ x,
                                            const void* __restrict__ gam,
                                            const void* __restrict__ bet,
                                            int xrow, int f, float mean, float rstd) {
    float xv = ldf<B16>(x, xrow + f);
    float gv = ldf<B16>(gam, f);
    float bv = ldf<B16>(bet, f);
    float xn = fmaf(xv - mean, rstd * gv, bv);
    float tt = fmaf(xn, 1.5f, 4.5f);  // t = (xn+3)/h, h=2/3
    float bb[6];
#pragma unroll
    for (int j = 0; j < 6; ++j) {
        float d = tt - (float)(j + 2);
        float a = fabsf(d);
        float a2 = d * d;
        float v1 = fmaf(fmaf(0.5f, a, -1.0f), a2, 0.66666669f);
        float c = fmaxf(2.0f - a, 0.0f);  // clamps a>=2 to 0 via cube
        float v2 = c * c * c * (1.0f / 6.0f);
        bb[j] = (a < 1.0f) ? v1 : v2;
    }
    uint4 o;
    o.x = pk2(fmaxf(xn, 0.f), bb[0]);
    o.y = pk2(bb[1], bb[2]);
    o.z = pk2(bb[3], bb[4]);
    o.w = pk2(bb[5], 0.f);
    return o;
}

// ---------------- fused GEMM ----------------
// 64 rows x 512 cols per block, BK=32, 4 waves (col-groups), each wave 64x128
// (acc 4x8 frags). Double-buffered LDS; one barrier per K-step; 2 blocks/CU.
// LDS slot layout (16B slots): A slot = mi*64 + l holds (row mi*16+(l&15),
// kchunk l>>4); B slot = cf*64 + l holds (col cf*16+(l&15), kchunk l>>4)
// -> frag reads are lane-sequential 1KB ds_read_b128 (conflict-free).
// B staged via source-permuted global_load_lds (wave-uniform dest base).
template <bool B16>
__device__ __forceinline__ void kan_gemm_body(
    const void* __restrict__ x,
    const float2* __restrict__ stats,
    const unsigned short* __restrict__ wt,
    const void* __restrict__ gam,
    const void* __restrict__ bet,
    const void* __restrict__ bias,
    void* __restrict__ out,
    unsigned short* __restrict__ Alds,   // 2 x 2048 shorts (4 KB each)
    unsigned short* __restrict__ Blds) { // 2 x 16384 shorts (32 KB each)

    const int tid = threadIdx.x;
    const int lane = tid & 63, wv = tid >> 6;   // wv 0..3 = col-group
    const int rtile = blockIdx.x;               // 0..511

    // A-gen: thread owns slot tid: row ar, kchunk aq
    const int ar = ((tid >> 6) << 4) | (tid & 15);
    const int aq = (tid >> 4) & 3;
    const int grow = rtile * 64 + ar;
    const float2 st = stats[grow];
    const float mean = st.x, rstd = st.y;
    const int xrow = grow * F_DIM;

    // B staging: slot s = wv*512 + i*64 + lane holds Wt col C, kchunk q
    const unsigned short* gsrc[8];
#pragma unroll
    for (int i = 0; i < 8; ++i) {
        int s = wv * 512 + i * 64 + lane;
        int C = ((s >> 6) << 4) | (s & 15);
        int q = (s >> 4) & 3;
        gsrc[i] = wt + (size_t)C * K_DIM + q * 8;
    }
    const int bbase = wv * 512 * 8;  // wave-uniform LDS element base

    const int lr = lane & 15, lq = lane >> 4;

    floatx4 acc[4][8];
#pragma unroll
    for (int mi = 0; mi < 4; ++mi)
#pragma unroll
        for (int ni = 0; ni < 8; ++ni) acc[mi][ni] = (floatx4){0.f, 0.f, 0.f, 0.f};

    // ---- prologue: stage k-step 0 into buffer 0 ----
#pragma unroll
    for (int i = 0; i < 8; ++i)
        __builtin_amdgcn_global_load_lds(
            (const __attribute__((address_space(1))) void*)gsrc[i],
            (__attribute__((address_space(3))) void*)&Blds[bbase + i * 64 * 8], 16, 0, 0);
    {
        uint4 p0 = gen_a_pack<B16>(x, gam, bet, xrow, aq, mean, rstd);
        *(uint4*)&Alds[tid * 8] = p0;
    }
    __syncthreads();

    // ---- main loop: compute k-step ks from buf[ks&1], stage ks+1 into other ----
    for (int ks = 0; ks < K_DIM / 32 - 1; ++ks) {
        const int cur = ks & 1, nxt = cur ^ 1;
        unsigned short* __restrict__ Ac = Alds + cur * 2048;
        unsigned short* __restrict__ An = Alds + nxt * 2048;
        unsigned short* __restrict__ Bc = Blds + cur * 16384;
        unsigned short* __restrict__ Bn = Blds + nxt * 16384;

        // B staging for ks+1 (8 x 16B per thread, wave-uniform dest base)
#pragma unroll
        for (int i = 0; i < 8; ++i)
            __builtin_amdgcn_global_load_lds(
                (const __attribute__((address_space(1))) void*)(gsrc[i] + (ks + 1) * 32),
                (__attribute__((address_space(3))) void*)&Bn[bbase + i * 64 * 8], 16, 0, 0);

        // fragments of current step (lane-sequential, conflict-free)
        short8 afr[4], bfr[8];
#pragma unroll
        for (int mi = 0; mi < 4; ++mi)
            afr[mi] = *(const short8*)&Ac[(mi * 64 + lane) * 8];
#pragma unroll
        for (int ni = 0; ni < 8; ++ni)
            bfr[ni] = *(const short8*)&Bc[((wv * 8 + ni) * 64 + lane) * 8];

        // A generation for ks+1 (independent of the MFMAs below -> overlaps)
        uint4 pkv = gen_a_pack<B16>(x, gam, bet, xrow, (ks + 1) * 4 + aq, mean, rstd);
        *(uint4*)&An[tid * 8] = pkv;

#pragma unroll
        for (int mi = 0; mi < 4; ++mi)
#pragma unroll
            for (int ni = 0; ni < 8; ++ni)
                acc[mi][ni] = __builtin_amdgcn_mfma_f32_16x16x32_bf16(
                    afr[mi], bfr[ni], acc[mi][ni], 0, 0, 0);

        __syncthreads();  // nxt buffer ready; cur free to overwrite next iter
    }

    // ---- final k-step (buffer 1), no staging ----
    {
        const unsigned short* Ac = Alds + 2048;
        const unsigned short* Bc = Blds + 16384;
        short8 afr[4], bfr[8];
#pragma unroll
        for (int mi = 0; mi < 4; ++mi)
            afr[mi] = *(const short8*)&Ac[(mi * 64 + lane) * 8];
#pragma unroll
        for (int ni = 0; ni < 8; ++ni)
            bfr[ni] = *(const short8*)&Bc[((wv * 8 + ni) * 64 + lane) * 8];
#pragma unroll
        for (int mi = 0; mi < 4; ++mi)
#pragma unroll
            for (int ni = 0; ni < 8; ++ni)
                acc[mi][ni] = __builtin_amdgcn_mfma_f32_16x16x32_bf16(
                    afr[mi], bfr[ni], acc[mi][ni], 0, 0, 0);
    }

    // ---- epilogue: + bias, store ----
    float biasv[8];
#pragma unroll
    for (int ni = 0; ni < 8; ++ni)
        biasv[ni] = ldf<B16>(bias, wv * 128 + ni * 16 + lr);
#pragma unroll
    for (int mi = 0; mi < 4; ++mi)
#pragma unroll
        for (int ni = 0; ni < 8; ++ni)
#pragma unroll
            for (int r = 0; r < 4; ++r) {
                int row = rtile * 64 + mi * 16 + lq * 4 + r;
                int col = wv * 128 + ni * 16 + lr;
                float val = acc[mi][ni][r] + biasv[ni];
                if (B16) ((unsigned short*)out)[(size_t)row * U_DIM + col] =
                    (unsigned short)(pk2(val, 0.f) & 0xffffu);
                else ((float*)out)[(size_t)row * U_DIM + col] = val;
            }
}
__global__ __launch_bounds__(256, 2) void kan_gemm(
    const void* __restrict__ x, const float2* __restrict__ stats,
    const unsigned short* __restrict__ wt, const void* __restrict__ gam,
    const void* __restrict__ bet, const void* __restrict__ bias,
    const void* __restrict__ grid, void* __restrict__ out) {
    // Shared memory declared ONCE here (not inside the template bodies) so the
    // <true>/<false> instantiations share it: 4+32 KB double-buffered = 72 KB.
    __shared__ __align__(16) unsigned short Alds[2 * 2048];    // 2 x 4 KB
    __shared__ __align__(16) unsigned short Blds[2 * 16384];   // 2 x 32 KB
    if (probe_bf16(grid)) kan_gemm_body<true>(x, stats, wt, gam, bet, bias, out, Alds, Blds);
    else                  kan_gemm_body<false>(x, stats, wt, gam, bet, bias, out, Alds, Blds);
}

extern "C" void kernel_launch(void* const* d_in, const int* in_sizes, int n_in,
                              void* d_out, int out_size, void* d_ws, size_t ws_size,
                              hipStream_t stream) {
    const void* x    = d_in[0];
    const void* gam  = d_in[1];
    const void* bet  = d_in[2];
    const void* bw   = d_in[3];
    const void* bb   = d_in[4];
    const void* sw   = d_in[5];
    const void* grid = d_in[6];  // uniform knots; also the dtype probe

    float2* stats = (float2*)d_ws;                                                  // 256 KB
    unsigned short* wt = (unsigned short*)((char*)d_ws + N_ROWS * sizeof(float2));  // 4 MB bf16

    hipLaunchKernelGGL(prep_k, dim3(N_ROWS / 4 + U_DIM * 128 / 256), dim3(256), 0, stream,
                       x, bw, sw, grid, stats, wt);
    hipLaunchKernelGGL(kan_gemm, dim3(N_ROWS / 64), dim3(256), 0, stream,
                       x, stats, wt, gam, bet, bb, grid, d_out);
}

// Round 3
// 393.868 us; speedup vs baseline: 1.1160x; 1.1160x over previous
//
#include <hip/hip_runtime.h>
#include <hip/hip_bf16.h>

// KANLinear fused: LayerNorm -> {relu, cubic B-spline basis} -> single bf16 MFMA GEMM.
// N=32768 rows, F=512, U=512. K = F*8 = 4096 ([relu, b0..b5, 0] per feature).
// R5: B-fragments read DIRECTLY from global wt (16 fully-used 64B lines per
// dwordx4 wave-load; no LDS staging, no global_load_lds, no vmcnt coupling).
// A through LDS, generated in GROUPS of 8 K-steps (1 feature/thread/step,
// interleaved into the step loop), double-buffered -> ONE __syncthreads per
// 8 K-steps. 64x512 tile, 4 waves, grid=512 -> 2 blocks/CU so barrier stalls
// in one block are covered by the other block's MFMAs.

#define N_ROWS 32768
#define F_DIM  512
#define U_DIM  512
#define K_DIM  4096

typedef short short8 __attribute__((ext_vector_type(8)));
typedef float floatx4 __attribute__((ext_vector_type(4)));

__device__ __forceinline__ float bf2f(unsigned short h) {
    return __uint_as_float(((unsigned int)h) << 16);
}
__device__ __forceinline__ bool probe_bf16(const void* grid) {
    // fp32: grid[0] == -3.0f exactly (0xC0400000). bf16-packed: 0xC015C040.
    return ((const unsigned int*)grid)[0] != 0xC0400000u;
}
template <bool B16>
__device__ __forceinline__ float ldf(const void* p, int i) {
    return B16 ? bf2f(((const unsigned short*)p)[i]) : ((const float*)p)[i];
}
template <bool B16>
__device__ __forceinline__ void ld4(const void* p, int i, float* o) {
    if (B16) {
        ushort4 v = *(const ushort4*)((const unsigned short*)p + i);
        o[0] = bf2f(v.x); o[1] = bf2f(v.y); o[2] = bf2f(v.z); o[3] = bf2f(v.w);
    } else {
        float4 v = *(const float4*)((const float*)p + i);
        o[0] = v.x; o[1] = v.y; o[2] = v.z; o[3] = v.w;
    }
}
__device__ __forceinline__ unsigned int pk2(float lo, float hi) {
    __hip_bfloat162 h = __float22bfloat162_rn(make_float2(lo, hi));
    return *reinterpret_cast<unsigned int*>(&h);
}

// ---------------- prep: per-row LayerNorm stats + Wt[u][k] build ----------------
template <bool B16>
__device__ __forceinline__ void ln_stats_body(const void* __restrict__ x,
                                              float2* __restrict__ stats, int bid) {
    int wave = threadIdx.x >> 6, lane = threadIdx.x & 63;
    int row = bid * 4 + wave;
    float v[8];
    ld4<B16>(x, row * F_DIM + lane * 8, v);
    ld4<B16>(x, row * F_DIM + lane * 8 + 4, v + 4);
    float s = 0.f, s2 = 0.f;
#pragma unroll
    for (int k = 0; k < 8; ++k) { s += v[k]; s2 += v[k] * v[k]; }
#pragma unroll
    for (int off = 32; off > 0; off >>= 1) {
        s  += __shfl_xor(s, off);
        s2 += __shfl_xor(s2, off);
    }
    if (lane == 0) {
        float mean = s * (1.0f / F_DIM);
        float var  = s2 * (1.0f / F_DIM) - mean * mean;
        stats[row] = make_float2(mean, rsqrtf(var + 1e-3f));
    }
}
template <bool B16>
__device__ __forceinline__ void build_wt_body(const void* __restrict__ bw,
                                              const void* __restrict__ sw,
                                              unsigned short* __restrict__ wt, int bid) {
    int idx = bid * 256 + threadIdx.x;  // 0 .. 512*128
    int u = idx & 511;
    int fq = idx >> 9;  // 0..127 -> features fq*4 .. fq*4+3
#pragma unroll
    for (int i = 0; i < 4; ++i) {
        int f = fq * 4 + i;
        uint4 w;
        w.x = pk2(ldf<B16>(bw, f * U_DIM + u),            ldf<B16>(sw, (f * 6 + 0) * U_DIM + u));
        w.y = pk2(ldf<B16>(sw, (f * 6 + 1) * U_DIM + u),  ldf<B16>(sw, (f * 6 + 2) * U_DIM + u));
        w.z = pk2(ldf<B16>(sw, (f * 6 + 3) * U_DIM + u),  ldf<B16>(sw, (f * 6 + 4) * U_DIM + u));
        w.w = pk2(ldf<B16>(sw, (f * 6 + 5) * U_DIM + u),  0.f);
        *(uint4*)(wt + (size_t)u * K_DIM + f * 8) = w;
    }
}
__global__ __launch_bounds__(256) void prep_k(const void* __restrict__ x,
                                              const void* __restrict__ bw,
                                              const void* __restrict__ sw,
                                              const void* __restrict__ grid,
                                              float2* __restrict__ stats,
                                              unsigned short* __restrict__ wt) {
    int bid = blockIdx.x;
    if (probe_bf16(grid)) {
        if (bid < N_ROWS / 4) ln_stats_body<true>(x, stats, bid);
        else                  build_wt_body<true>(bw, sw, wt, bid - N_ROWS / 4);
    } else {
        if (bid < N_ROWS / 4) ln_stats_body<false>(x, stats, bid);
        else                  build_wt_body<false>(bw, sw, wt, bid - N_ROWS / 4);
    }
}

// ---------------- A-element generator: [relu, b0..b5, 0] -> one 16B LDS slot ----
template <bool B16>
__device__ __forceinline__ void gen_one(const void* __restrict__ x,
                                        const void* __restrict__ gam,
                                        const void* __restrict__ bet,
                                        int xrow, int f, float mean, float rstd,
                                        unsigned short* __restrict__ dst) {
    float xv = ldf<B16>(x, xrow + f);
    float gv = ldf<B16>(gam, f);
    float bv = ldf<B16>(bet, f);
    float xn = fmaf(xv - mean, rstd * gv, bv);
    float tt = fmaf(xn, 1.5f, 4.5f);  // t = (xn+3)/h, h=2/3
    float bb[6];
#pragma unroll
    for (int j = 0; j < 6; ++j) {
        float d = tt - (float)(j + 2);
        float a = fabsf(d);
        float a2 = d * d;
        float v1 = fmaf(fmaf(0.5f, a, -1.0f), a2, 0.66666669f);
        float c = fmaxf(2.0f - a, 0.0f);  // clamps a>=2 to 0 via cube
        float v2 = c * c * c * (1.0f / 6.0f);
        bb[j] = (a < 1.0f) ? v1 : v2;
    }
    uint4 o;
    o.x = pk2(fmaxf(xn, 0.f), bb[0]);
    o.y = pk2(bb[1], bb[2]);
    o.z = pk2(bb[3], bb[4]);
    o.w = pk2(bb[5], 0.f);
    *(uint4*)dst = o;
}

// ---------------- fused GEMM ----------------
// 64 rows x 512 cols per block, 4 waves (col-groups wc=0..3), each wave 64x128
// (acc 4x8 frags of 16x16x32). B-frags: direct global_load_dwordx4 from wt
// (lane l, frag ni: wt[(wc*128+ni*16+(l&15))*4096 + ks*32 + (l>>4)*8], 16
// fully-used 64B lines per wave-instruction; one line = one step's k-range).
// A: LDS double buffer of 8-step groups (2 x 32 KB). Per step each thread
// generates ONE feature of the NEXT group (interleaved with MFMAs); one
// __syncthreads per 8 steps. A slot layout (16B slots, per step-region):
// slot(ar,q) = ((ar>>4)*4+q)*16 + (ar&15) -> afr reads lane-sequential,
// conflict-free; ds_writes lane-sequential, conflict-free.
template <bool B16>
__device__ __forceinline__ void kan_gemm_body(
    const void* __restrict__ x,
    const float2* __restrict__ stats,
    const unsigned short* __restrict__ wt,
    const void* __restrict__ gam,
    const void* __restrict__ bet,
    const void* __restrict__ bias,
    void* __restrict__ out,
    unsigned short* __restrict__ Alds) {  // 2 x 16384 shorts (32 KB each)

    const int tid = threadIdx.x;
    const int lane = tid & 63, wc = tid >> 6;   // wc 0..3 = col-group
    const int rtile = blockIdx.x;               // 0..511
    const int lr = lane & 15, lq = lane >> 4;

    // A-gen: thread owns (row ar, kchunk aq)
    const int ar = ((tid >> 6) << 4) | (tid & 15);
    const int aq = (tid >> 4) & 3;
    const float2 st = stats[rtile * 64 + ar];
    const float mean = st.x, rstd = st.y;
    const int xrow = (rtile * 64 + ar) * F_DIM;
    const int aslot = (((ar >> 4) * 4 + aq) * 16 + (ar & 15)) * 8;  // element offset

    // B pointers: frag ni, lane l -> col C = wc*128+ni*16+lr, kchunk lq
    const unsigned short* bptr[8];
#pragma unroll
    for (int ni = 0; ni < 8; ++ni)
        bptr[ni] = wt + (size_t)(wc * 128 + ni * 16 + lr) * K_DIM + lq * 8;

    floatx4 acc[4][8];
#pragma unroll
    for (int mi = 0; mi < 4; ++mi)
#pragma unroll
        for (int ni = 0; ni < 8; ++ni) acc[mi][ni] = (floatx4){0.f, 0.f, 0.f, 0.f};

    // ---- prologue: generate group 0 (steps 0..7) into buffer 0 ----
#pragma unroll
    for (int s = 0; s < 8; ++s)
        gen_one<B16>(x, gam, bet, xrow, s * 4 + aq, mean, rstd,
                     &Alds[s * 2048 + aslot]);
    __syncthreads();

    // ---- main loop over 16 groups of 8 K-steps ----
    for (int g = 0; g < 16; ++g) {
        unsigned short* __restrict__ Ac = Alds + (g & 1) * 16384;
        unsigned short* __restrict__ An = Alds + ((g & 1) ^ 1) * 16384;
#pragma unroll
        for (int s = 0; s < 8; ++s) {
            const int ks = g * 8 + s;
            // B frags straight from global (L1/L2-resident wt)
            short8 bfr[8];
#pragma unroll
            for (int ni = 0; ni < 8; ++ni)
                bfr[ni] = *(const short8*)(bptr[ni] + ks * 32);
            // A frags from LDS (conflict-free lane-sequential)
            short8 afr[4];
#pragma unroll
            for (int mi = 0; mi < 4; ++mi)
                afr[mi] = *(const short8*)&Ac[s * 2048 + (mi * 64 + lane) * 8];
            // generate step s of NEXT group (independent -> overlaps MFMAs)
            if (g < 15)
                gen_one<B16>(x, gam, bet, xrow, (ks + 8) * 4 + aq, mean, rstd,
                             &An[s * 2048 + aslot]);
#pragma unroll
            for (int mi = 0; mi < 4; ++mi)
#pragma unroll
                for (int ni = 0; ni < 8; ++ni)
                    acc[mi][ni] = __builtin_amdgcn_mfma_f32_16x16x32_bf16(
                        afr[mi], bfr[ni], acc[mi][ni], 0, 0, 0);
        }
        __syncthreads();  // next-group A visible; vmcnt already drained by uses
    }

    // ---- epilogue: + bias, store ----
    float biasv[8];
#pragma unroll
    for (int ni = 0; ni < 8; ++ni)
        biasv[ni] = ldf<B16>(bias, wc * 128 + ni * 16 + lr);
#pragma unroll
    for (int mi = 0; mi < 4; ++mi)
#pragma unroll
        for (int ni = 0; ni < 8; ++ni)
#pragma unroll
            for (int r = 0; r < 4; ++r) {
                int row = rtile * 64 + mi * 16 + lq * 4 + r;
                int col = wc * 128 + ni * 16 + lr;
                float val = acc[mi][ni][r] + biasv[ni];
                if (B16) ((unsigned short*)out)[(size_t)row * U_DIM + col] =
                    (unsigned short)(pk2(val, 0.f) & 0xffffu);
                else ((float*)out)[(size_t)row * U_DIM + col] = val;
            }
}
__global__ __launch_bounds__(256, 2) void kan_gemm(
    const void* __restrict__ x, const float2* __restrict__ stats,
    const unsigned short* __restrict__ wt, const void* __restrict__ gam,
    const void* __restrict__ bet, const void* __restrict__ bias,
    const void* __restrict__ grid, void* __restrict__ out) {
    // Shared memory declared ONCE here so the <true>/<false> instantiations
    // share it: 2 x 32 KB A group-buffers = 64 KB -> 2 blocks/CU.
    __shared__ __align__(16) unsigned short Alds[2 * 16384];
    if (probe_bf16(grid)) kan_gemm_body<true>(x, stats, wt, gam, bet, bias, out, Alds);
    else                  kan_gemm_body<false>(x, stats, wt, gam, bet, bias, out, Alds);
}

extern "C" void kernel_launch(void* const* d_in, const int* in_sizes, int n_in,
                              void* d_out, int out_size, void* d_ws, size_t ws_size,
                              hipStream_t stream) {
    const void* x    = d_in[0];
    const void* gam  = d_in[1];
    const void* bet  = d_in[2];
    const void* bw   = d_in[3];
    const void* bb   = d_in[4];
    const void* sw   = d_in[5];
    const void* grid = d_in[6];  // uniform knots; also the dtype probe

    float2* stats = (float2*)d_ws;                                                  // 256 KB
    unsigned short* wt = (unsigned short*)((char*)d_ws + N_ROWS * sizeof(float2));  // 4 MB bf16

    hipLaunchKernelGGL(prep_k, dim3(N_ROWS / 4 + U_DIM * 128 / 256), dim3(256), 0, stream,
                       x, bw, sw, grid, stats, wt);
    hipLaunchKernelGGL(kan_gemm, dim3(N_ROWS / 64), dim3(256), 0, stream,
                       x, stats, wt, gam, bet, bb, grid, d_out);
}

// Round 5
// 331.739 us; speedup vs baseline: 1.3250x; 1.1873x over previous
//
#include <hip/hip_runtime.h>
#include <hip/hip_bf16.h>

// KANLinear fused: LayerNorm -> {relu, cubic B-spline basis} -> single bf16 MFMA GEMM.
// N=32768 rows, F=512, U=512. K = F*8 = 4096 ([relu, b0..b5, 0] per feature).
// R6b: 128x512 tile (full U), 8 waves, grid=256 (1 block/CU, 101 KB LDS).
//  - B staged to LDS via global_load_lds (32 KB/step, double-buffered, issued at
//    step top -> drained by step-end __syncthreads under ~1242 cyc of MFMA).
//  - A generated in 2-step GROUPS (thread owns features 8g+4p+w, p=0,1): x
//    scalars prefetched one full group ahead into rotating registers -> x HBM
//    latency off the barrier path. 1 spline-gen/thread/step.
//  - LN stats computed in-kernel (4 thr/row + shfl reduce); gamma/beta in LDS;
//    prep kernel is build_wt only.
//  - s_setprio(1) around the MFMA cluster.
//  - LDS kept at 101 KB (<= verified 128 KiB envelope; R6's 133 KB was the
//    suspected container-killer).

#define N_ROWS 32768
#define F_DIM  512
#define U_DIM  512
#define K_DIM  4096

typedef short short8 __attribute__((ext_vector_type(8)));
typedef unsigned short ushort8v __attribute__((ext_vector_type(8)));
typedef float floatx4 __attribute__((ext_vector_type(4)));

__device__ __forceinline__ float bf2f(unsigned short h) {
    return __uint_as_float(((unsigned int)h) << 16);
}
__device__ __forceinline__ bool probe_bf16(const void* grid) {
    // fp32: grid[0] == -3.0f exactly (0xC0400000). bf16-packed: 0xC015C040.
    return ((const unsigned int*)grid)[0] != 0xC0400000u;
}
template <bool B16>
__device__ __forceinline__ float ldf(const void* p, int i) {
    return B16 ? bf2f(((const unsigned short*)p)[i]) : ((const float*)p)[i];
}
template <bool B16>
__device__ __forceinline__ void ld8f(const void* p, int i, float* o) {
    if (B16) {
        ushort8v v = *(const ushort8v*)((const unsigned short*)p + i);
#pragma unroll
        for (int k = 0; k < 8; ++k) o[k] = bf2f(v[k]);
    } else {
        float4 a = *(const float4*)((const float*)p + i);
        float4 b = *(const float4*)((const float*)p + i + 4);
        o[0]=a.x; o[1]=a.y; o[2]=a.z; o[3]=a.w; o[4]=b.x; o[5]=b.y; o[6]=b.z; o[7]=b.w;
    }
}
__device__ __forceinline__ unsigned int pk2(float lo, float hi) {
    __hip_bfloat162 h = __float22bfloat162_rn(make_float2(lo, hi));
    return *reinterpret_cast<unsigned int*>(&h);
}
__device__ __forceinline__ void gld_lds16(const unsigned short* g, unsigned short* l) {
    __builtin_amdgcn_global_load_lds((const __attribute__((address_space(1))) void*)g,
                                     (__attribute__((address_space(3))) void*)l, 16, 0, 0);
}

// ---------------- prep: build Wt[u][k] (bf16), k = f*8 + j ----------------
template <bool B16>
__device__ __forceinline__ void build_wt_body(const void* __restrict__ bw,
                                              const void* __restrict__ sw,
                                              unsigned short* __restrict__ wt, int bid) {
    int idx = bid * 256 + threadIdx.x;  // 0 .. 512*128
    int u = idx & 511;
    int fq = idx >> 9;  // 0..127 -> features fq*4 .. fq*4+3
#pragma unroll
    for (int i = 0; i < 4; ++i) {
        int f = fq * 4 + i;
        uint4 w;
        w.x = pk2(ldf<B16>(bw, f * U_DIM + u),            ldf<B16>(sw, (f * 6 + 0) * U_DIM + u));
        w.y = pk2(ldf<B16>(sw, (f * 6 + 1) * U_DIM + u),  ldf<B16>(sw, (f * 6 + 2) * U_DIM + u));
        w.z = pk2(ldf<B16>(sw, (f * 6 + 3) * U_DIM + u),  ldf<B16>(sw, (f * 6 + 4) * U_DIM + u));
        w.w = pk2(ldf<B16>(sw, (f * 6 + 5) * U_DIM + u),  0.f);
        *(uint4*)(wt + (size_t)u * K_DIM + f * 8) = w;
    }
}
__global__ __launch_bounds__(256) void prep_k(const void* __restrict__ bw,
                                              const void* __restrict__ sw,
                                              const void* __restrict__ grid,
                                              unsigned short* __restrict__ wt) {
    if (probe_bf16(grid)) build_wt_body<true>(bw, sw, wt, blockIdx.x);
    else                  build_wt_body<false>(bw, sw, wt, blockIdx.x);
}

// ---------------- spline A-element: [relu, b0..b5, 0] -> 16B ----------------
__device__ __forceinline__ uint4 spline_pack(float xv, float gv, float bv,
                                             float mean, float rstd) {
    float xn = fmaf(xv - mean, rstd * gv, bv);
    float tt = fmaf(xn, 1.5f, 4.5f);  // t = (xn+3)/h, h=2/3
    float bb[6];
#pragma unroll
    for (int j = 0; j < 6; ++j) {
        float d = tt - (float)(j + 2);
        float a = fabsf(d);
        float a2 = d * d;
        float v1 = fmaf(fmaf(0.5f, a, -1.0f), a2, 0.66666669f);
        float c = fmaxf(2.0f - a, 0.0f);  // clamps a>=2 to 0 via cube
        float v2 = c * c * c * (1.0f / 6.0f);
        bb[j] = (a < 1.0f) ? v1 : v2;
    }
    uint4 o;
    o.x = pk2(fmaxf(xn, 0.f), bb[0]);
    o.y = pk2(bb[1], bb[2]);
    o.z = pk2(bb[3], bb[4]);
    o.w = pk2(bb[5], 0.f);
    return o;
}

// ---------------- fused GEMM ----------------
// 128 rows x 512 cols per block, BK=32, 8 waves (wr=wv>>2 row-group, wc=wv&3
// col-group), each wave 64x128 (acc 4x8 frags of 16x16x32).
// LDS slot layout (16B slots): A region p (p = step&1 within group): slot(ar,q)
// = ((ar>>4)*4+q)*16 + (ar&15); B: slot(cf,l) = cf*64 + l (cf = col frag 0..31,
// col = cf*16 + (l&15), kchunk = l>>4) -> all frag reads lane-sequential 1KB
// ds_read_b128, conflict-free. B staged via source-permuted global_load_lds.
// A-gen: thread (ar = tid&127, w = tid>>7) owns features 8g + 4p + w of group g
// (one per step), written one group ahead into the alternate A buffer.
template <bool B16>
__device__ __forceinline__ void kan_gemm_body(
    const void* __restrict__ x,
    const unsigned short* __restrict__ wt,
    const void* __restrict__ gam,
    const void* __restrict__ bet,
    const void* __restrict__ bias,
    void* __restrict__ out,
    unsigned short* __restrict__ Alds,   // 2 x 8192 shorts (16 KB each)
    unsigned short* __restrict__ Blds,   // 2 x 16384 shorts (32 KB each)
    float2* __restrict__ gb,             // 512 (gamma, beta)
    float2* __restrict__ st) {           // 128 (mean, rstd)

    const int tid = threadIdx.x;               // 0..511
    const int lane = tid & 63, wv = tid >> 6;  // wv 0..7
    const int rtile = blockIdx.x;              // 0..255
    const int lr = lane & 15, lq = lane >> 4;
    const int wr = wv >> 2, wc = wv & 3;

    // ---- gamma/beta -> LDS ----
    gb[tid] = make_float2(ldf<B16>(gam, tid), ldf<B16>(bet, tid));

    // ---- in-block LN stats: 4 threads per row, shfl-quad reduce ----
    {
        const int row = tid >> 2, sub = tid & 3;
        const int base = (rtile * 128 + row) * F_DIM + sub * 128;
        float s = 0.f, s2 = 0.f;
#pragma unroll
        for (int i = 0; i < 16; ++i) {
            float v[8];
            ld8f<B16>(x, base + i * 8, v);
#pragma unroll
            for (int k = 0; k < 8; ++k) { s += v[k]; s2 += v[k] * v[k]; }
        }
        s += __shfl_xor(s, 1); s2 += __shfl_xor(s2, 1);
        s += __shfl_xor(s, 2); s2 += __shfl_xor(s2, 2);
        if (sub == 0) {
            float mean = s * (1.0f / F_DIM);
            float var  = s2 * (1.0f / F_DIM) - mean * mean;
            st[row] = make_float2(mean, rsqrtf(var + 1e-3f));
        }
    }

    // ---- B staging sources (slot s = wv*256 + i*64 + lane -> col C, kchunk q) ----
    const unsigned short* gsrc[4];
#pragma unroll
    for (int i = 0; i < 4; ++i) {
        int s = wv * 256 + i * 64 + lane;
        int C = ((s >> 6) << 4) | (s & 15);
        int q = (s >> 4) & 3;
        gsrc[i] = wt + (size_t)C * K_DIM + q * 8;
    }
    // stage step 0 into B buffer 0
#pragma unroll
    for (int i = 0; i < 4; ++i)
        gld_lds16(gsrc[i], &Blds[wv * 2048 + i * 512]);

    __syncthreads();  // stats + gb visible; B0 staged

    // ---- per-thread A-gen setup ----
    const int ar = tid & 127, w = tid >> 7;   // w = feature sub-slot 0..3
    const float2 ms = st[ar];
    const float mean = ms.x, rstd = ms.y;
    const int xrow = (rtile * 128 + ar) * F_DIM;
    // shorts offset of this thread's slot within a step-region (q = w)
    const int aoff = (ar >> 4) * 512 + w * 128 + (ar & 15) * 8;

    // prologue: gen group 0 (features w, 4+w) into A buffer 0 regions 0,1
    {
        float x0 = ldf<B16>(x, xrow + w);
        float x1 = ldf<B16>(x, xrow + 4 + w);
        float2 ga = gb[w], gc = gb[4 + w];
        *(uint4*)&Alds[aoff]        = spline_pack(x0, ga.x, ga.y, mean, rstd);
        *(uint4*)&Alds[4096 + aoff] = spline_pack(x1, gc.x, gc.y, mean, rstd);
    }
    // issue x for group 1 (features 8+w, 12+w) into rotating raw regs
    unsigned short xu0, xu1; float xf0, xf1;
    if (B16) {
        xu0 = ((const unsigned short*)x)[xrow + 8 + w];
        xu1 = ((const unsigned short*)x)[xrow + 12 + w];
    } else {
        xf0 = ((const float*)x)[xrow + 8 + w];
        xf1 = ((const float*)x)[xrow + 12 + w];
    }
    __syncthreads();  // A0 visible
    float xC[2];
    if (B16) { xC[0] = bf2f(xu0); xC[1] = bf2f(xu1); }
    else     { xC[0] = xf0;       xC[1] = xf1; }

    floatx4 acc[4][8];
#pragma unroll
    for (int mi = 0; mi < 4; ++mi)
#pragma unroll
        for (int ni = 0; ni < 8; ++ni) acc[mi][ni] = (floatx4){0.f, 0.f, 0.f, 0.f};

    // ---- main loop: 64 groups x 2 K-steps ----
    for (int g = 0; g < 64; ++g) {
        unsigned short* __restrict__ Ac = Alds + (g & 1) * 8192;
        unsigned short* __restrict__ An = Alds + ((g & 1) ^ 1) * 8192;
        if (g < 62) {  // prefetch x for group g+2 (consumed during group g+1)
            int fx = (g + 2) * 8 + w;
            if (B16) {
                xu0 = ((const unsigned short*)x)[xrow + fx];
                xu1 = ((const unsigned short*)x)[xrow + fx + 4];
            } else {
                xf0 = ((const float*)x)[xrow + fx];
                xf1 = ((const float*)x)[xrow + fx + 4];
            }
        }
        const bool dogen = (g < 63);
        const int f0n = (g + 1) * 8 + w;
#pragma unroll
        for (int p = 0; p < 2; ++p) {
            const int ks = g * 2 + p;
            unsigned short* __restrict__ Bc = Blds + (ks & 1) * 16384;
            unsigned short* __restrict__ Bn = Blds + ((ks & 1) ^ 1) * 16384;
            // stage B(ks+1) into the other buffer (drained at this step's barrier)
            if (ks < 127) {
#pragma unroll
                for (int i = 0; i < 4; ++i)
                    gld_lds16(gsrc[i] + (ks + 1) * 32, &Bn[wv * 2048 + i * 512]);
            }
            // fragments of step ks (lane-sequential, conflict-free)
            short8 afr[4], bfr[8];
#pragma unroll
            for (int mi = 0; mi < 4; ++mi)
                afr[mi] = *(const short8*)&Ac[p * 4096 + ((wr * 4 + mi) * 64 + lane) * 8];
#pragma unroll
            for (int ni = 0; ni < 8; ++ni)
                bfr[ni] = *(const short8*)&Bc[((wc * 8 + ni) * 64 + lane) * 8];
            // gen one feature of group g+1 (VALU, overlaps ds/MFMA)
            if (dogen) {
                float2 g2 = gb[f0n + 4 * p];
                *(uint4*)&An[p * 4096 + aoff] =
                    spline_pack(xC[p], g2.x, g2.y, mean, rstd);
            }
            __builtin_amdgcn_s_setprio(1);
#pragma unroll
            for (int mi = 0; mi < 4; ++mi)
#pragma unroll
                for (int ni = 0; ni < 8; ++ni)
                    acc[mi][ni] = __builtin_amdgcn_mfma_f32_16x16x32_bf16(
                        afr[mi], bfr[ni], acc[mi][ni], 0, 0, 0);
            __builtin_amdgcn_s_setprio(0);
            __syncthreads();
        }
        if (g < 62) {  // rotate raw x regs -> floats for next group's gens
            if (B16) { xC[0] = bf2f(xu0); xC[1] = bf2f(xu1); }
            else     { xC[0] = xf0;       xC[1] = xf1; }
        }
    }

    // ---- epilogue: + bias, store ----
    float biasv[8];
#pragma unroll
    for (int ni = 0; ni < 8; ++ni)
        biasv[ni] = ldf<B16>(bias, wc * 128 + ni * 16 + lr);
#pragma unroll
    for (int mi = 0; mi < 4; ++mi)
#pragma unroll
        for (int ni = 0; ni < 8; ++ni)
#pragma unroll
            for (int r = 0; r < 4; ++r) {
                int row = rtile * 128 + wr * 64 + mi * 16 + lq * 4 + r;
                int col = wc * 128 + ni * 16 + lr;
                float val = acc[mi][ni][r] + biasv[ni];
                if (B16) ((unsigned short*)out)[(size_t)row * U_DIM + col] =
                    (unsigned short)(pk2(val, 0.f) & 0xffffu);
                else ((float*)out)[(size_t)row * U_DIM + col] = val;
            }
}
__global__ __launch_bounds__(512, 2) void kan_gemm(
    const void* __restrict__ x, const unsigned short* __restrict__ wt,
    const void* __restrict__ gam, const void* __restrict__ bet,
    const void* __restrict__ bias, const void* __restrict__ grid,
    void* __restrict__ out) {
    // LDS declared ONCE here so <true>/<false> instantiations share it:
    // A 2x16 KB + B 2x32 KB + gb 4 KB + st 1 KB = 101 KB -> 1 block/CU.
    __shared__ __align__(16) unsigned short Alds[2 * 8192];
    __shared__ __align__(16) unsigned short Blds[2 * 16384];
    __shared__ float2 gb_lds[512];
    __shared__ float2 st_lds[128];
    if (probe_bf16(grid))
        kan_gemm_body<true>(x, wt, gam, bet, bias, out, Alds, Blds, gb_lds, st_lds);
    else
        kan_gemm_body<false>(x, wt, gam, bet, bias, out, Alds, Blds, gb_lds, st_lds);
}

extern "C" void kernel_launch(void* const* d_in, const int* in_sizes, int n_in,
                              void* d_out, int out_size, void* d_ws, size_t ws_size,
                              hipStream_t stream) {
    const void* x    = d_in[0];
    const void* gam  = d_in[1];
    const void* bet  = d_in[2];
    const void* bw   = d_in[3];
    const void* bb   = d_in[4];
    const void* sw   = d_in[5];
    const void* grid = d_in[6];  // uniform knots; also the dtype probe

    unsigned short* wt = (unsigned short*)d_ws;  // 4 MB bf16

    hipLaunchKernelGGL(prep_k, dim3(U_DIM * 128 / 256), dim3(256), 0, stream,
                       bw, sw, grid, wt);
    hipLaunchKernelGGL(kan_gemm, dim3(N_ROWS / 128), dim3(512), 0, stream,
                       x, wt, gam, bet, bb, grid, d_out);
}